// Round 1
// baseline (1846.135 us; speedup 1.0000x reference)
//
#include <hip/hip_runtime.h>
#include <cstdint>
#include <cstddef>

#define EPS 1e-5f

static __device__ __forceinline__ void atomicAddF(float* p, float v) {
    __hip_atomic_fetch_add(p, v, __ATOMIC_RELAXED, __HIP_MEMORY_SCOPE_AGENT);
}

// ---- kernel 1: degree counts (out-degree by src for dinv, in-degree by dst for CSR) ----
__global__ void k_count(const int* __restrict__ src, const int* __restrict__ dst,
                        int E, int* __restrict__ deg_src, int* __restrict__ cnt_dst) {
    int i = blockIdx.x * blockDim.x + threadIdx.x;
    if (i < E) {
        atomicAdd(&deg_src[src[i]], 1);
        atomicAdd(&cnt_dst[dst[i]], 1);
    }
}

// ---- kernel 2: dinv + CSR row allocation (wave-scan + one atomic per wave; rows need not be ordered) ----
__global__ void k_dinv_alloc(const int* __restrict__ deg, const int* __restrict__ cnt,
                             int n, float* __restrict__ dinv, int* __restrict__ row_start,
                             int* __restrict__ total) {
    int i = blockIdx.x * blockDim.x + threadIdx.x;
    int lane = threadIdx.x & 63;
    if (i < n) {
        float d = (float)deg[i];
        dinv[i] = d > 0.f ? rsqrtf(d) : 0.f;
    }
    int c = (i < n) ? cnt[i] : 0;
    int incl = c;
    #pragma unroll
    for (int off = 1; off < 64; off <<= 1) {
        int v = __shfl_up(incl, off);
        if (lane >= off) incl += v;
    }
    int wtot = __shfl(incl, 63);
    int base = 0;
    if (lane == 63) base = atomicAdd(total, wtot);
    base = __shfl(base, 63);
    if (i < n) row_start[i] = base + incl - c;
}

// ---- kernel 3: fill CSR (by dst) with src index and edge weight ----
__global__ void k_fill(const int* __restrict__ src, const int* __restrict__ dst, int E,
                       const float* __restrict__ dinv, const int* __restrict__ row_start,
                       int* __restrict__ cursor, int* __restrict__ csr_src,
                       float* __restrict__ csr_norm) {
    int i = blockIdx.x * blockDim.x + threadIdx.x;
    if (i < E) {
        int s = src[i], d = dst[i];
        int pos = atomicAdd(&cursor[d], 1);
        int idx = row_start[d] + pos;
        csr_src[idx] = s;
        csr_norm[idx] = -dinv[s] * dinv[d];
    }
}

// ---- kernel 4: lhat SpMM as pure gather: one wave per output row, lane owns 2 feature cols ----
__global__ void k_gather(const float* __restrict__ v, const int* __restrict__ row_start,
                         const int* __restrict__ cnt, const int* __restrict__ csr_src,
                         const float* __restrict__ csr_norm, float* __restrict__ out, int n) {
    int row = blockIdx.x * 4 + (threadIdx.x >> 6);
    if (row >= n) return;
    int lane = threadIdx.x & 63;
    int base = row_start[row];
    int deg = cnt[row];
    const float2* v2 = (const float2*)v;
    float ax = 0.f, ay = 0.f;
    for (int j = 0; j < deg; ++j) {
        int s = csr_src[base + j];       // uniform across wave -> cache broadcast
        float w = csr_norm[base + j];
        float2 xv = v2[(size_t)s * 64 + lane];  // 512B contiguous per wave
        ax = fmaf(w, xv.x, ax);
        ay = fmaf(w, xv.y, ay);
    }
    float2 r; r.x = ax; r.y = ay;
    ((float2*)out)[(size_t)row * 64 + lane] = r;
}

// ---- kernel 5: effective weights: out = x@(W0-W2) + tx1@W1 + z@(2*W2) ----
__global__ void k_weff(const float* __restrict__ W, float* __restrict__ Weff) {
    int i = blockIdx.x * blockDim.x + threadIdx.x;
    if (i < 16384) {
        float w0 = W[i], w1 = W[16384 + i], w2 = W[32768 + i];
        Weff[i] = w0 - w2;
        Weff[16384 + i] = w1;
        Weff[32768 + i] = 2.f * w2;
    }
}

// ---- kernel 6: fused 3-hop GEMM + bias + PReLU + BN-stat accumulation ----
// block: 256 threads; tile 64 rows x 128 cols; thread (ty,tx) = 4 rows x 8 cols
__global__ __launch_bounds__(256) void k_gemm(
        const float* __restrict__ A0, const float* __restrict__ A1, const float* __restrict__ A2,
        const float* __restrict__ Weff, const float* __restrict__ bias,
        const float* __restrict__ aprelu, float* __restrict__ out,
        float* __restrict__ sums, float* __restrict__ sumsq, int n) {
    __shared__ float At[64][68];    // 64 rows x 64 k (padded to 68 -> 16B-aligned rows, low conflict)
    __shared__ float Wl[64][128];   // 64 k x 128 cols
    int t = threadIdx.x;
    int tx = t & 15, ty = t >> 4;
    int row0 = blockIdx.x * 64;
    float acc[4][8];
    #pragma unroll
    for (int q = 0; q < 4; ++q)
        #pragma unroll
        for (int j = 0; j < 8; ++j) acc[q][j] = 0.f;

    const float* As[3] = {A0, A1, A2};
    for (int h = 0; h < 3; ++h) {
        const float* A = As[h];
        const float* Wh = Weff + h * 16384;
        for (int c = 0; c < 2; ++c) {
            // stage A tile: 64 rows x 64 k
            {
                int lr = t >> 4;             // 0..15
                int lk = (t & 15) * 4;       // 0..60
                #pragma unroll
                for (int i = 0; i < 4; ++i) {
                    int r = lr + i * 16;
                    int row = row0 + r;
                    float4 vv = make_float4(0.f, 0.f, 0.f, 0.f);
                    if (row < n) vv = *(const float4*)&A[(size_t)row * 128 + c * 64 + lk];
                    *(float4*)&At[r][lk] = vv;
                }
                // stage W tile: 64 k x 128 cols
                const float* Wp = Wh + c * 64 * 128;
                int wk = t >> 5;             // 0..7
                int wc = (t & 31) * 4;       // 0..124
                #pragma unroll
                for (int i = 0; i < 8; ++i) {
                    *(float4*)&Wl[wk + i * 8][wc] = *(const float4*)&Wp[(wk + i * 8) * 128 + wc];
                }
            }
            __syncthreads();
            #pragma unroll 2
            for (int k = 0; k < 64; ++k) {
                float b[8];
                *(float4*)&b[0] = *(float4*)&Wl[k][tx * 8];
                *(float4*)&b[4] = *(float4*)&Wl[k][tx * 8 + 4];
                #pragma unroll
                for (int q = 0; q < 4; ++q) {
                    float a = At[ty * 4 + q][k];
                    #pragma unroll
                    for (int j = 0; j < 8; ++j) acc[q][j] = fmaf(a, b[j], acc[q][j]);
                }
            }
            __syncthreads();
        }
    }

    // epilogue: bias + PReLU, store, per-column sum/sumsq
    float ap = aprelu[0];
    float s8[8], q8[8];
    #pragma unroll
    for (int j = 0; j < 8; ++j) { s8[j] = 0.f; q8[j] = 0.f; }
    #pragma unroll
    for (int q = 0; q < 4; ++q) {
        int row = row0 + ty * 4 + q;
        if (row < n) {
            float v[8];
            #pragma unroll
            for (int j = 0; j < 8; ++j) {
                float o = acc[q][j] + bias[tx * 8 + j];
                o = o >= 0.f ? o : ap * o;
                v[j] = o;
                s8[j] += o;
                q8[j] = fmaf(o, o, q8[j]);
            }
            float4* op = (float4*)&out[(size_t)row * 128 + tx * 8];
            op[0] = *(float4*)&v[0];
            op[1] = *(float4*)&v[4];
        }
    }
    // reduce across lanes sharing the same tx (lane, lane^16, lane^32, lane^48)
    #pragma unroll
    for (int j = 0; j < 8; ++j) {
        s8[j] += __shfl_xor(s8[j], 16);
        s8[j] += __shfl_xor(s8[j], 32);
        q8[j] += __shfl_xor(q8[j], 16);
        q8[j] += __shfl_xor(q8[j], 32);
    }
    if ((threadIdx.x & 48) == 0) {   // one lane per tx per wave
        #pragma unroll
        for (int j = 0; j < 8; ++j) {
            atomicAddF(&sums[tx * 8 + j], s8[j]);
            atomicAddF(&sumsq[tx * 8 + j], q8[j]);
        }
    }
}

// ---- kernel 7: BN scale/shift from stats ----
__global__ void k_bnfinal(const float* __restrict__ sums, const float* __restrict__ sumsq,
                          const float* __restrict__ gamma, const float* __restrict__ beta,
                          float* __restrict__ bnp, float n) {
    int c = threadIdx.x;
    float mean = sums[c] / n;
    float var = sumsq[c] / n - mean * mean;
    float sc = gamma[c] * rsqrtf(var + EPS);
    bnp[c] = sc;
    bnp[128 + c] = beta[c] - mean * sc;
}

// ---- kernel 8: apply BN in place ----
__global__ void k_bnapply(float* __restrict__ out, const float* __restrict__ bnp, int total4) {
    int i = blockIdx.x * blockDim.x + threadIdx.x;
    if (i >= total4) return;
    float4 v = ((float4*)out)[i];
    int c = (i * 4) & 127;
    float4 sc = *(const float4*)&bnp[c];
    float4 sh = *(const float4*)&bnp[128 + c];
    v.x = fmaf(v.x, sc.x, sh.x);
    v.y = fmaf(v.y, sc.y, sh.y);
    v.z = fmaf(v.z, sc.z, sh.z);
    v.w = fmaf(v.w, sc.w, sh.w);
    ((float4*)out)[i] = v;
}

extern "C" void kernel_launch(void* const* d_in, const int* in_sizes, int n_in,
                              void* d_out, int out_size, void* d_ws, size_t ws_size,
                              hipStream_t stream) {
    const float* x      = (const float*)d_in[0];
    const int*   ei     = (const int*)d_in[1];
    const float* W      = (const float*)d_in[2];
    const float* bias   = (const float*)d_in[3];
    const float* aprelu = (const float*)d_in[4];
    const float* gamma  = (const float*)d_in[5];
    const float* beta   = (const float*)d_in[6];
    int n = in_sizes[0] / 128;
    int E = in_sizes[1] / 2;
    const int* src = ei;
    const int* dst = ei + E;

    char* ws = (char*)d_ws;
    size_t off = 0;
    auto carve = [&](size_t bytes) {
        char* p = ws + off;
        off = (off + bytes + 511) & ~(size_t)511;
        return p;
    };
    float* tx1      = (float*)carve((size_t)n * 128 * 4);
    size_t zbeg = off;
    int*   deg_src  = (int*)carve((size_t)n * 4);
    int*   cnt_dst  = (int*)carve((size_t)n * 4);
    int*   cursor   = (int*)carve((size_t)n * 4);
    int*   total    = (int*)carve(256);
    float* sums     = (float*)carve(512);
    float* sumsq    = (float*)carve(512);
    size_t zend = off;
    float* dinv     = (float*)carve((size_t)n * 4);
    int*   row_start= (int*)carve((size_t)n * 4);
    int*   csr_src  = (int*)carve((size_t)E * 4);
    float* csr_norm = (float*)carve((size_t)E * 4);
    float* Weff     = (float*)carve(3 * 128 * 128 * 4);
    float* bnp      = (float*)carve(256 * 4);
    (void)ws_size; (void)n_in; (void)out_size;

    float* z = (float*)d_out;   // z = lhat(tx1) lives in d_out; GEMM reads its own rows before writing

    hipMemsetAsync(ws + zbeg, 0, zend - zbeg, stream);

    int eb = (E + 255) / 256;
    int nb = (n + 255) / 256;
    k_count<<<eb, 256, 0, stream>>>(src, dst, E, deg_src, cnt_dst);
    k_dinv_alloc<<<nb, 256, 0, stream>>>(deg_src, cnt_dst, n, dinv, row_start, total);
    k_fill<<<eb, 256, 0, stream>>>(src, dst, E, dinv, row_start, cursor, csr_src, csr_norm);
    k_weff<<<64, 256, 0, stream>>>(W, Weff);
    int gb = (n + 3) / 4;
    k_gather<<<gb, 256, 0, stream>>>(x, row_start, cnt_dst, csr_src, csr_norm, tx1, n);
    k_gather<<<gb, 256, 0, stream>>>(tx1, row_start, cnt_dst, csr_src, csr_norm, z, n);
    int mb = (n + 63) / 64;
    k_gemm<<<mb, 256, 0, stream>>>(x, tx1, z, Weff, bias, aprelu, (float*)d_out, sums, sumsq, n);
    k_bnfinal<<<1, 128, 0, stream>>>(sums, sumsq, gamma, beta, bnp, (float)n);
    int total4 = n * 32;
    k_bnapply<<<(total4 + 255) / 256, 256, 0, stream>>>((float*)d_out, bnp, total4);
}

// Round 2
// 680.234 us; speedup vs baseline: 2.7140x; 2.7140x over previous
//
#include <hip/hip_runtime.h>
#include <cstdint>
#include <cstddef>

#define EPS 1e-5f

typedef __attribute__((ext_vector_type(8))) short short8;
typedef __attribute__((ext_vector_type(4))) float f32x4;

static __device__ __forceinline__ void atomicAddF(float* p, float v) {
    __hip_atomic_fetch_add(p, v, __ATOMIC_RELAXED, __HIP_MEMORY_SCOPE_AGENT);
}

// round-to-nearest-even f32 -> bf16 bits
static __device__ __forceinline__ short f2bf(float f) {
    uint32_t u = __float_as_uint(f);
    u += 0x7FFFu + ((u >> 16) & 1u);
    return (short)(u >> 16);
}

// ---- kernel 1: degree counts ----
__global__ void k_count(const int* __restrict__ src, const int* __restrict__ dst,
                        int E, int* __restrict__ deg_src, int* __restrict__ cnt_dst) {
    int i = blockIdx.x * blockDim.x + threadIdx.x;
    if (i < E) {
        atomicAdd(&deg_src[src[i]], 1);
        atomicAdd(&cnt_dst[dst[i]], 1);
    }
}

// ---- kernel 2: dinv + CSR row allocation ----
__global__ void k_dinv_alloc(const int* __restrict__ deg, const int* __restrict__ cnt,
                             int n, float* __restrict__ dinv, int* __restrict__ row_start,
                             int* __restrict__ total) {
    int i = blockIdx.x * blockDim.x + threadIdx.x;
    int lane = threadIdx.x & 63;
    if (i < n) {
        float d = (float)deg[i];
        dinv[i] = d > 0.f ? rsqrtf(d) : 0.f;
    }
    int c = (i < n) ? cnt[i] : 0;
    int incl = c;
    #pragma unroll
    for (int off = 1; off < 64; off <<= 1) {
        int v = __shfl_up(incl, off);
        if (lane >= off) incl += v;
    }
    int wtot = __shfl(incl, 63);
    int base = 0;
    if (lane == 63) base = atomicAdd(total, wtot);
    base = __shfl(base, 63);
    if (i < n) row_start[i] = base + incl - c;
}

// ---- kernel 3: fill CSR (by dst) ----
__global__ void k_fill(const int* __restrict__ src, const int* __restrict__ dst, int E,
                       const float* __restrict__ dinv, const int* __restrict__ row_start,
                       int* __restrict__ cursor, int* __restrict__ csr_src,
                       float* __restrict__ csr_norm) {
    int i = blockIdx.x * blockDim.x + threadIdx.x;
    if (i < E) {
        int s = src[i], d = dst[i];
        int pos = atomicAdd(&cursor[d], 1);
        int idx = row_start[d] + pos;
        csr_src[idx] = s;
        csr_norm[idx] = -dinv[s] * dinv[d];
    }
}

// ---- kernel 4: lhat SpMM gather: one wave per row, lane owns 2 cols ----
__global__ void k_gather(const float* __restrict__ v, const int* __restrict__ row_start,
                         const int* __restrict__ cnt, const int* __restrict__ csr_src,
                         const float* __restrict__ csr_norm, float* __restrict__ out, int n) {
    int row = blockIdx.x * 4 + (threadIdx.x >> 6);
    if (row >= n) return;
    int lane = threadIdx.x & 63;
    int base = row_start[row];
    int deg = cnt[row];
    const float2* v2 = (const float2*)v;
    float ax = 0.f, ay = 0.f;
    for (int j = 0; j < deg; ++j) {
        int s = csr_src[base + j];
        float w = csr_norm[base + j];
        float2 xv = v2[(size_t)s * 64 + lane];
        ax = fmaf(w, xv.x, ax);
        ay = fmaf(w, xv.y, ay);
    }
    float2 r; r.x = ax; r.y = ay;
    ((float2*)out)[(size_t)row * 64 + lane] = r;
}

// ---- kernel 5: effective weights, TRANSPOSED bf16: WT[c][h*128+k] ----
// hop0 = W0 - W2, hop1 = W1, hop2 = 2*W2
__global__ void k_wefft(const float* __restrict__ W, short* __restrict__ WT) {
    int i = blockIdx.x * blockDim.x + threadIdx.x;
    if (i < 16384) {
        int k = i >> 7, c = i & 127;
        float w0 = W[i], w1 = W[16384 + i], w2 = W[32768 + i];
        WT[(size_t)c * 384 + k]       = f2bf(w0 - w2);
        WT[(size_t)c * 384 + 128 + k] = f2bf(w1);
        WT[(size_t)c * 384 + 256 + k] = f2bf(2.f * w2);
    }
}

// ---- kernel 6: bf16 MFMA GEMM: out[128-row tile] = [x|tx1|z] @ Weff + bias, PReLU, BN stats ----
// 256 threads = 4 waves (2x2); wave owns 64x64 = 4x4 fragments of 16x16x32 MFMA
__global__ __launch_bounds__(256) void k_gemm_mfma(
        const float* __restrict__ A0, const float* __restrict__ A1, const float* __restrict__ A2,
        const short* __restrict__ WT, const float* __restrict__ bias,
        const float* __restrict__ aprelu, float* __restrict__ out,
        float* __restrict__ sums, float* __restrict__ sumsq, int n) {
    // LDS tiles: [128 rows][64 k] bf16, 128 B/row, XOR block-swizzled within each row
    __shared__ __align__(16) short Alds[128 * 64];
    __shared__ __align__(16) short Blds[128 * 64];

    int t = threadIdx.x;
    int lane = t & 63;
    int w = t >> 6;
    int wr = w >> 1, wc = w & 1;
    int row0 = blockIdx.x * 128;

    f32x4 acc[4][4];
    #pragma unroll
    for (int m = 0; m < 4; ++m)
        #pragma unroll
        for (int nn = 0; nn < 4; ++nn) acc[m][nn] = (f32x4){0.f, 0.f, 0.f, 0.f};

    #pragma unroll
    for (int ht = 0; ht < 6; ++ht) {
        const int h = ht >> 1, c = ht & 1;
        const float* A = (h == 0) ? A0 : (h == 1) ? A1 : A2;

        if (ht) __syncthreads();   // previous tile fully consumed

        // --- stage B tile via global_load_lds (16B/lane, linear LDS dest, pre-swizzled src)
        {
            #pragma unroll
            for (int i = 0; i < 4; ++i) {
                int rB = w * 32 + i * 8 + (lane >> 3);
                int blkB = (lane & 7) ^ (rB & 7);
                const short* srcB = WT + (size_t)rB * 384 + h * 128 + c * 64 + blkB * 8;
                __builtin_amdgcn_global_load_lds(
                    (const __attribute__((address_space(1))) void*)srcB,
                    (__attribute__((address_space(3))) void*)&Blds[(w * 32 + i * 8) * 64],
                    16, 0, 0);
            }
        }
        // --- stage A tile: reg-stage fp32 -> bf16 (thread owns half a row)
        {
            int r = t >> 1;                 // 0..127
            int half = t & 1;
            int grow = row0 + r; if (grow >= n) grow = n - 1;
            const float4* src = (const float4*)(A + (size_t)grow * 128 + c * 64 + half * 32);
            float4 v[8];
            #pragma unroll
            for (int j = 0; j < 8; ++j) v[j] = src[j];
            #pragma unroll
            for (int jj = 0; jj < 4; ++jj) {
                short8 o;
                float4 a = v[jj * 2], b = v[jj * 2 + 1];
                o[0] = f2bf(a.x); o[1] = f2bf(a.y); o[2] = f2bf(a.z); o[3] = f2bf(a.w);
                o[4] = f2bf(b.x); o[5] = f2bf(b.y); o[6] = f2bf(b.z); o[7] = f2bf(b.w);
                int blk = (half * 4 + jj) ^ (r & 7);
                *(short8*)((char*)Alds + r * 128 + blk * 16) = o;
            }
        }
        __syncthreads();   // drains vmcnt (global_load_lds) + lgkmcnt

        // --- MFMA: 2 k-subtiles of 32
        #pragma unroll
        for (int kk = 0; kk < 2; ++kk) {
            short8 af[4], bf[4];
            #pragma unroll
            for (int m = 0; m < 4; ++m) {
                int row = wr * 64 + m * 16 + (lane & 15);
                int blk = (kk * 4 + (lane >> 4)) ^ (row & 7);
                af[m] = *(const short8*)((const char*)Alds + row * 128 + blk * 16);
            }
            #pragma unroll
            for (int nn = 0; nn < 4; ++nn) {
                int col = wc * 64 + nn * 16 + (lane & 15);
                int blk = (kk * 4 + (lane >> 4)) ^ (col & 7);
                bf[nn] = *(const short8*)((const char*)Blds + col * 128 + blk * 16);
            }
            #pragma unroll
            for (int m = 0; m < 4; ++m)
                #pragma unroll
                for (int nn = 0; nn < 4; ++nn)
                    acc[m][nn] = __builtin_amdgcn_mfma_f32_16x16x32_bf16(
                        af[m], bf[nn], acc[m][nn], 0, 0, 0);
        }
    }

    // --- epilogue: bias + PReLU + store + BN stats
    float ap = aprelu[0];
    #pragma unroll
    for (int nn = 0; nn < 4; ++nn) {
        int col = wc * 64 + nn * 16 + (lane & 15);
        float bs = bias[col];
        float s = 0.f, q = 0.f;
        #pragma unroll
        for (int m = 0; m < 4; ++m) {
            int rbase = row0 + wr * 64 + m * 16 + (lane >> 4) * 4;
            #pragma unroll
            for (int r = 0; r < 4; ++r) {
                int row = rbase + r;
                if (row < n) {
                    float o = acc[m][nn][r] + bs;
                    o = o >= 0.f ? o : ap * o;
                    out[(size_t)row * 128 + col] = o;
                    s += o; q = fmaf(o, o, q);
                }
            }
        }
        s += __shfl_xor(s, 16); s += __shfl_xor(s, 32);
        q += __shfl_xor(q, 16); q += __shfl_xor(q, 32);
        if ((lane >> 4) == 0) {
            atomicAddF(&sums[col], s);
            atomicAddF(&sumsq[col], q);
        }
    }
}

// ---- kernel 7: BN scale/shift from stats ----
__global__ void k_bnfinal(const float* __restrict__ sums, const float* __restrict__ sumsq,
                          const float* __restrict__ gamma, const float* __restrict__ beta,
                          float* __restrict__ bnp, float n) {
    int c = threadIdx.x;
    float mean = sums[c] / n;
    float var = sumsq[c] / n - mean * mean;
    float sc = gamma[c] * rsqrtf(var + EPS);
    bnp[c] = sc;
    bnp[128 + c] = beta[c] - mean * sc;
}

// ---- kernel 8: apply BN in place ----
__global__ void k_bnapply(float* __restrict__ out, const float* __restrict__ bnp, int total4) {
    int i = blockIdx.x * blockDim.x + threadIdx.x;
    if (i >= total4) return;
    float4 v = ((float4*)out)[i];
    int c = (i * 4) & 127;
    float4 sc = *(const float4*)&bnp[c];
    float4 sh = *(const float4*)&bnp[128 + c];
    v.x = fmaf(v.x, sc.x, sh.x);
    v.y = fmaf(v.y, sc.y, sh.y);
    v.z = fmaf(v.z, sc.z, sh.z);
    v.w = fmaf(v.w, sc.w, sh.w);
    ((float4*)out)[i] = v;
}

extern "C" void kernel_launch(void* const* d_in, const int* in_sizes, int n_in,
                              void* d_out, int out_size, void* d_ws, size_t ws_size,
                              hipStream_t stream) {
    const float* x      = (const float*)d_in[0];
    const int*   ei     = (const int*)d_in[1];
    const float* W      = (const float*)d_in[2];
    const float* bias   = (const float*)d_in[3];
    const float* aprelu = (const float*)d_in[4];
    const float* gamma  = (const float*)d_in[5];
    const float* beta   = (const float*)d_in[6];
    int n = in_sizes[0] / 128;
    int E = in_sizes[1] / 2;
    const int* src = ei;
    const int* dst = ei + E;

    char* ws = (char*)d_ws;
    size_t off = 0;
    auto carve = [&](size_t bytes) {
        char* p = ws + off;
        off = (off + bytes + 511) & ~(size_t)511;
        return p;
    };
    float* tx1      = (float*)carve((size_t)n * 128 * 4);
    size_t zbeg = off;
    int*   deg_src  = (int*)carve((size_t)n * 4);
    int*   cnt_dst  = (int*)carve((size_t)n * 4);
    int*   cursor   = (int*)carve((size_t)n * 4);
    int*   total    = (int*)carve(256);
    float* sums     = (float*)carve(512);
    float* sumsq    = (float*)carve(512);
    size_t zend = off;
    float* dinv     = (float*)carve((size_t)n * 4);
    int*   row_start= (int*)carve((size_t)n * 4);
    int*   csr_src  = (int*)carve((size_t)E * 4);
    float* csr_norm = (float*)carve((size_t)E * 4);
    short* WT       = (short*)carve((size_t)128 * 384 * 2);
    float* bnp      = (float*)carve(256 * 4);
    (void)ws_size; (void)n_in; (void)out_size;

    float* z = (float*)d_out;   // z lives in d_out; GEMM reads only its own rows before writing

    hipMemsetAsync(ws + zbeg, 0, zend - zbeg, stream);

    int eb = (E + 255) / 256;
    int nb = (n + 255) / 256;
    k_count<<<eb, 256, 0, stream>>>(src, dst, E, deg_src, cnt_dst);
    k_dinv_alloc<<<nb, 256, 0, stream>>>(deg_src, cnt_dst, n, dinv, row_start, total);
    k_fill<<<eb, 256, 0, stream>>>(src, dst, E, dinv, row_start, cursor, csr_src, csr_norm);
    k_wefft<<<64, 256, 0, stream>>>(W, WT);
    int gb = (n + 3) / 4;
    k_gather<<<gb, 256, 0, stream>>>(x, row_start, cnt_dst, csr_src, csr_norm, tx1, n);
    k_gather<<<gb, 256, 0, stream>>>(tx1, row_start, cnt_dst, csr_src, csr_norm, z, n);
    int mb = (n + 127) / 128;
    k_gemm_mfma<<<mb, 256, 0, stream>>>(x, tx1, z, WT, bias, aprelu, (float*)d_out,
                                        sums, sumsq, n);
    k_bnfinal<<<1, 128, 0, stream>>>(sums, sumsq, gamma, beta, bnp, (float)n);
    int total4 = n * 32;
    k_bnapply<<<(total4 + 255) / 256, 256, 0, stream>>>((float*)d_out, bnp, total4);
}

// Round 3
// 455.035 us; speedup vs baseline: 4.0571x; 1.4949x over previous
//
#include <hip/hip_runtime.h>
#include <cstdint>
#include <cstddef>

#define EPS 1e-5f

typedef __attribute__((ext_vector_type(8))) short short8;
typedef __attribute__((ext_vector_type(4))) float f32x4;

static __device__ __forceinline__ void atomicAddF(float* p, float v) {
    __hip_atomic_fetch_add(p, v, __ATOMIC_RELAXED, __HIP_MEMORY_SCOPE_AGENT);
}

// round-to-nearest-even f32 -> bf16 bits
static __device__ __forceinline__ short f2bf(float f) {
    uint32_t u = __float_as_uint(f);
    u += 0x7FFFu + ((u >> 16) & 1u);
    return (short)(u >> 16);
}
static __device__ __forceinline__ float bf2f(short s) {
    return __uint_as_float(((uint32_t)(uint16_t)s) << 16);
}

// ---- kernel 1: degree counts ----
__global__ void k_count(const int* __restrict__ src, const int* __restrict__ dst,
                        int E, int* __restrict__ deg_src, int* __restrict__ cnt_dst) {
    int i = blockIdx.x * blockDim.x + threadIdx.x;
    if (i < E) {
        atomicAdd(&deg_src[src[i]], 1);
        atomicAdd(&cnt_dst[dst[i]], 1);
    }
}

// ---- kernel 2: dinv + CSR row allocation (wave scan + 1 atomic/wave) ----
__global__ void k_dinv_alloc(const int* __restrict__ deg, const int* __restrict__ cnt,
                             int n, float* __restrict__ dinv, int* __restrict__ row_start,
                             int* __restrict__ total) {
    int i = blockIdx.x * blockDim.x + threadIdx.x;
    int lane = threadIdx.x & 63;
    if (i < n) {
        float d = (float)deg[i];
        dinv[i] = d > 0.f ? rsqrtf(d) : 0.f;
    }
    int c = (i < n) ? cnt[i] : 0;
    int incl = c;
    #pragma unroll
    for (int off = 1; off < 64; off <<= 1) {
        int v = __shfl_up(incl, off);
        if (lane >= off) incl += v;
    }
    int wtot = __shfl(incl, 63);
    int base = 0;
    if (lane == 63) base = atomicAdd(total, wtot);
    base = __shfl(base, 63);
    if (i < n) row_start[i] = base + incl - c;
}

// ---- kernel 3: fill CSR (by dst): fused {src, norm_bits} int2 ----
__global__ void k_fill(const int* __restrict__ src, const int* __restrict__ dst, int E,
                       const float* __restrict__ dinv, const int* __restrict__ row_start,
                       int* __restrict__ cursor, int2* __restrict__ csr) {
    int i = blockIdx.x * blockDim.x + threadIdx.x;
    if (i < E) {
        int s = src[i], d = dst[i];
        int pos = atomicAdd(&cursor[d], 1);
        int2 v;
        v.x = s;
        v.y = __float_as_int(-dinv[s] * dinv[d]);
        csr[row_start[d] + pos] = v;
    }
}

// ---- kernel 4: fp32 -> bf16 bulk convert ----
__global__ void k_tobf(const float* __restrict__ x, short* __restrict__ xbf, int total8) {
    int i = blockIdx.x * blockDim.x + threadIdx.x;
    if (i >= total8) return;
    const float4* s = (const float4*)x + (size_t)i * 2;
    float4 a = s[0], b = s[1];
    short8 o;
    o[0] = f2bf(a.x); o[1] = f2bf(a.y); o[2] = f2bf(a.z); o[3] = f2bf(a.w);
    o[4] = f2bf(b.x); o[5] = f2bf(b.y); o[6] = f2bf(b.z); o[7] = f2bf(b.w);
    ((short8*)xbf)[i] = o;
}

// ---- kernel 5: lhat gather, bf16 input. Wave = 1 row; 4 groups of 16 lanes,
//      each group gathers a different edge (16 lanes x short8 = 256B row read).
template <int OUT_BF>
__global__ void k_gather_bf(const short* __restrict__ xbf, const int* __restrict__ row_start,
                            const int* __restrict__ cnt, const int2* __restrict__ csr,
                            void* __restrict__ outp, int n) {
    int row = blockIdx.x * 4 + (threadIdx.x >> 6);
    if (row >= n) return;
    int lane = threadIdx.x & 63;
    int gr = lane >> 4, lc = lane & 15;
    int base = row_start[row];
    int deg = cnt[row];
    float acc[8];
    #pragma unroll
    for (int t = 0; t < 8; ++t) acc[t] = 0.f;
    #pragma unroll 2
    for (int j = 0; j < deg; j += 4) {
        int jj = j + gr;
        bool val = jj < deg;
        int2 sw = csr[base + (val ? jj : 0)];
        float w = val ? __int_as_float(sw.y) : 0.f;
        short8 xv = *(const short8*)(xbf + (size_t)sw.x * 128 + lc * 8);
        #pragma unroll
        for (int t = 0; t < 8; ++t) acc[t] = fmaf(w, bf2f(xv[t]), acc[t]);
    }
    #pragma unroll
    for (int t = 0; t < 8; ++t) {
        acc[t] += __shfl_xor(acc[t], 32);
        acc[t] += __shfl_xor(acc[t], 16);
    }
    if (gr == 0) {
        if (OUT_BF) {
            short8 o;
            #pragma unroll
            for (int t = 0; t < 8; ++t) o[t] = f2bf(acc[t]);
            *(short8*)((short*)outp + (size_t)row * 128 + lc * 8) = o;
        } else {
            float4 a, b;
            a.x = acc[0]; a.y = acc[1]; a.z = acc[2]; a.w = acc[3];
            b.x = acc[4]; b.y = acc[5]; b.z = acc[6]; b.w = acc[7];
            float4* op = (float4*)((float*)outp + (size_t)row * 128 + lc * 8);
            op[0] = a; op[1] = b;
        }
    }
}

// ---- kernel 6: effective weights, TRANSPOSED bf16: WT[c][h*128+k] ----
__global__ void k_wefft(const float* __restrict__ W, short* __restrict__ WT) {
    int i = blockIdx.x * blockDim.x + threadIdx.x;
    if (i < 16384) {
        int k = i >> 7, c = i & 127;
        float w0 = W[i], w1 = W[16384 + i], w2 = W[32768 + i];
        WT[(size_t)c * 384 + k]       = f2bf(w0 - w2);
        WT[(size_t)c * 384 + 128 + k] = f2bf(w1);
        WT[(size_t)c * 384 + 256 + k] = f2bf(2.f * w2);
    }
}

// ---- kernel 7: bf16 MFMA GEMM: out = [x|tx1|z] @ Weff + bias, PReLU, BN stats ----
__global__ __launch_bounds__(256) void k_gemm_mfma(
        const short* __restrict__ A0bf, const short* __restrict__ A1bf,
        const float* __restrict__ A2f,
        const short* __restrict__ WT, const float* __restrict__ bias,
        const float* __restrict__ aprelu, float* __restrict__ out,
        float* __restrict__ sums, float* __restrict__ sumsq, int n) {
    __shared__ __align__(16) short Alds[128 * 64];
    __shared__ __align__(16) short Blds[128 * 64];

    int t = threadIdx.x;
    int lane = t & 63;
    int w = t >> 6;
    int wr = w >> 1, wc = w & 1;
    int row0 = blockIdx.x * 128;

    f32x4 acc[4][4];
    #pragma unroll
    for (int m = 0; m < 4; ++m)
        #pragma unroll
        for (int nn = 0; nn < 4; ++nn) acc[m][nn] = (f32x4){0.f, 0.f, 0.f, 0.f};

    #pragma unroll
    for (int ht = 0; ht < 6; ++ht) {
        const int h = ht >> 1, c = ht & 1;

        if (ht) __syncthreads();

        // --- stage B tile (WT) via global_load_lds, pre-swizzled src
        #pragma unroll
        for (int i = 0; i < 4; ++i) {
            int rB = w * 32 + i * 8 + (lane >> 3);
            int blkB = (lane & 7) ^ (rB & 7);
            const short* srcB = WT + (size_t)rB * 384 + h * 128 + c * 64 + blkB * 8;
            __builtin_amdgcn_global_load_lds(
                (const __attribute__((address_space(1))) void*)srcB,
                (__attribute__((address_space(3))) void*)&Blds[(w * 32 + i * 8) * 64],
                16, 0, 0);
        }
        // --- stage A tile
        if (h < 2) {
            const short* Abf = (h == 0) ? A0bf : A1bf;
            #pragma unroll
            for (int i = 0; i < 4; ++i) {
                int rA = w * 32 + i * 8 + (lane >> 3);
                int grow = row0 + rA; if (grow >= n) grow = n - 1;
                int blkA = (lane & 7) ^ (rA & 7);
                const short* srcA = Abf + (size_t)grow * 128 + c * 64 + blkA * 8;
                __builtin_amdgcn_global_load_lds(
                    (const __attribute__((address_space(1))) void*)srcA,
                    (__attribute__((address_space(3))) void*)&Alds[(w * 32 + i * 8) * 64],
                    16, 0, 0);
            }
        } else {
            // fp32 z from d_out: reg-stage + convert (thread owns half a row)
            int r = t >> 1;
            int half = t & 1;
            int grow = row0 + r; if (grow >= n) grow = n - 1;
            const float4* src = (const float4*)(A2f + (size_t)grow * 128 + c * 64 + half * 32);
            float4 v[8];
            #pragma unroll
            for (int j = 0; j < 8; ++j) v[j] = src[j];
            #pragma unroll
            for (int jj = 0; jj < 4; ++jj) {
                short8 o;
                float4 a = v[jj * 2], b = v[jj * 2 + 1];
                o[0] = f2bf(a.x); o[1] = f2bf(a.y); o[2] = f2bf(a.z); o[3] = f2bf(a.w);
                o[4] = f2bf(b.x); o[5] = f2bf(b.y); o[6] = f2bf(b.z); o[7] = f2bf(b.w);
                int blk = (half * 4 + jj) ^ (r & 7);
                *(short8*)((char*)Alds + r * 128 + blk * 16) = o;
            }
        }
        __syncthreads();

        // --- MFMA: 2 k-subtiles of 32
        #pragma unroll
        for (int kk = 0; kk < 2; ++kk) {
            short8 af[4], bfr[4];
            #pragma unroll
            for (int m = 0; m < 4; ++m) {
                int row = wr * 64 + m * 16 + (lane & 15);
                int blk = (kk * 4 + (lane >> 4)) ^ (row & 7);
                af[m] = *(const short8*)((const char*)Alds + row * 128 + blk * 16);
            }
            #pragma unroll
            for (int nn = 0; nn < 4; ++nn) {
                int col = wc * 64 + nn * 16 + (lane & 15);
                int blk = (kk * 4 + (lane >> 4)) ^ (col & 7);
                bfr[nn] = *(const short8*)((const char*)Blds + col * 128 + blk * 16);
            }
            #pragma unroll
            for (int m = 0; m < 4; ++m)
                #pragma unroll
                for (int nn = 0; nn < 4; ++nn)
                    acc[m][nn] = __builtin_amdgcn_mfma_f32_16x16x32_bf16(
                        af[m], bfr[nn], acc[m][nn], 0, 0, 0);
        }
    }

    // --- epilogue: bias + PReLU + store + BN stats
    float ap = aprelu[0];
    #pragma unroll
    for (int nn = 0; nn < 4; ++nn) {
        int col = wc * 64 + nn * 16 + (lane & 15);
        float bs = bias[col];
        float s = 0.f, q = 0.f;
        #pragma unroll
        for (int m = 0; m < 4; ++m) {
            int rbase = row0 + wr * 64 + m * 16 + (lane >> 4) * 4;
            #pragma unroll
            for (int r = 0; r < 4; ++r) {
                int row = rbase + r;
                if (row < n) {
                    float o = acc[m][nn][r] + bs;
                    o = o >= 0.f ? o : ap * o;
                    out[(size_t)row * 128 + col] = o;
                    s += o; q = fmaf(o, o, q);
                }
            }
        }
        s += __shfl_xor(s, 16); s += __shfl_xor(s, 32);
        q += __shfl_xor(q, 16); q += __shfl_xor(q, 32);
        if ((lane >> 4) == 0) {
            atomicAddF(&sums[col], s);
            atomicAddF(&sumsq[col], q);
        }
    }
}

// ---- kernel 8: BN scale/shift from stats ----
__global__ void k_bnfinal(const float* __restrict__ sums, const float* __restrict__ sumsq,
                          const float* __restrict__ gamma, const float* __restrict__ beta,
                          float* __restrict__ bnp, float n) {
    int c = threadIdx.x;
    float mean = sums[c] / n;
    float var = sumsq[c] / n - mean * mean;
    float sc = gamma[c] * rsqrtf(var + EPS);
    bnp[c] = sc;
    bnp[128 + c] = beta[c] - mean * sc;
}

// ---- kernel 9: apply BN in place ----
__global__ void k_bnapply(float* __restrict__ out, const float* __restrict__ bnp, int total4) {
    int i = blockIdx.x * blockDim.x + threadIdx.x;
    if (i >= total4) return;
    float4 v = ((float4*)out)[i];
    int c = (i * 4) & 127;
    float4 sc = *(const float4*)&bnp[c];
    float4 sh = *(const float4*)&bnp[128 + c];
    v.x = fmaf(v.x, sc.x, sh.x);
    v.y = fmaf(v.y, sc.y, sh.y);
    v.z = fmaf(v.z, sc.z, sh.z);
    v.w = fmaf(v.w, sc.w, sh.w);
    ((float4*)out)[i] = v;
}

extern "C" void kernel_launch(void* const* d_in, const int* in_sizes, int n_in,
                              void* d_out, int out_size, void* d_ws, size_t ws_size,
                              hipStream_t stream) {
    const float* x      = (const float*)d_in[0];
    const int*   ei     = (const int*)d_in[1];
    const float* W      = (const float*)d_in[2];
    const float* bias   = (const float*)d_in[3];
    const float* aprelu = (const float*)d_in[4];
    const float* gamma  = (const float*)d_in[5];
    const float* beta   = (const float*)d_in[6];
    int n = in_sizes[0] / 128;
    int E = in_sizes[1] / 2;
    const int* src = ei;
    const int* dst = ei + E;

    char* ws = (char*)d_ws;
    size_t off = 0;
    auto carve = [&](size_t bytes) {
        char* p = ws + off;
        off = (off + bytes + 511) & ~(size_t)511;
        return p;
    };
    short* xbf      = (short*)carve((size_t)n * 128 * 2);
    short* tx1bf    = (short*)carve((size_t)n * 128 * 2);
    size_t zbeg = off;
    int*   deg_src  = (int*)carve((size_t)n * 4);
    int*   cnt_dst  = (int*)carve((size_t)n * 4);
    int*   cursor   = (int*)carve((size_t)n * 4);
    int*   total    = (int*)carve(256);
    float* sums     = (float*)carve(512);
    float* sumsq    = (float*)carve(512);
    size_t zend = off;
    float* dinv     = (float*)carve((size_t)n * 4);
    int*   row_start= (int*)carve((size_t)n * 4);
    int2*  csr      = (int2*)carve((size_t)E * 8);
    short* WT       = (short*)carve((size_t)128 * 384 * 2);
    float* bnp      = (float*)carve(256 * 4);
    (void)ws_size; (void)n_in; (void)out_size;

    float* z = (float*)d_out;   // z (fp32) lives in d_out; GEMM reads own rows before writing

    hipMemsetAsync(ws + zbeg, 0, zend - zbeg, stream);

    int eb = (E + 255) / 256;
    int nb = (n + 255) / 256;
    k_count<<<eb, 256, 0, stream>>>(src, dst, E, deg_src, cnt_dst);
    k_dinv_alloc<<<nb, 256, 0, stream>>>(deg_src, cnt_dst, n, dinv, row_start, total);
    k_fill<<<eb, 256, 0, stream>>>(src, dst, E, dinv, row_start, cursor, csr);
    k_wefft<<<64, 256, 0, stream>>>(W, WT);
    int t8 = n * 16;   // n*128/8
    k_tobf<<<(t8 + 255) / 256, 256, 0, stream>>>(x, xbf, t8);
    int gb = (n + 3) / 4;
    k_gather_bf<1><<<gb, 256, 0, stream>>>(xbf, row_start, cnt_dst, csr, tx1bf, n);
    k_gather_bf<0><<<gb, 256, 0, stream>>>(tx1bf, row_start, cnt_dst, csr, z, n);
    int mb = (n + 127) / 128;
    k_gemm_mfma<<<mb, 256, 0, stream>>>(xbf, tx1bf, z, WT, bias, aprelu, (float*)d_out,
                                        sums, sumsq, n);
    k_bnfinal<<<1, 128, 0, stream>>>(sums, sumsq, gamma, beta, bnp, (float)n);
    int total4 = n * 32;
    k_bnapply<<<(total4 + 255) / 256, 256, 0, stream>>>((float*)d_out, bnp, total4);
}

// Round 4
// 448.571 us; speedup vs baseline: 4.1156x; 1.0144x over previous
//
#include <hip/hip_runtime.h>
#include <cstdint>
#include <cstddef>

#define EPS 1e-5f

typedef __attribute__((ext_vector_type(8))) short short8;
typedef __attribute__((ext_vector_type(4))) float f32x4;

static __device__ __forceinline__ void atomicAddF(float* p, float v) {
    __hip_atomic_fetch_add(p, v, __ATOMIC_RELAXED, __HIP_MEMORY_SCOPE_AGENT);
}

// round-to-nearest-even f32 -> bf16 bits
static __device__ __forceinline__ short f2bf(float f) {
    uint32_t u = __float_as_uint(f);
    u += 0x7FFFu + ((u >> 16) & 1u);
    return (short)(u >> 16);
}
static __device__ __forceinline__ float bf2f(short s) {
    return __uint_as_float(((uint32_t)(uint16_t)s) << 16);
}

// ---- kernel 1: degree counts, 8-way privatized (copy per blockIdx&7 ~ per XCD) ----
// priv layout: deg copies [r*n + i] for r=0..7, cnt copies [(8+r)*n + i]
__global__ void k_count_priv(const int* __restrict__ src, const int* __restrict__ dst,
                             int E, int* __restrict__ priv, int n) {
    int i = blockIdx.x * blockDim.x + threadIdx.x;
    int r = blockIdx.x & 7;
    int* __restrict__ degp = priv + (size_t)r * n;
    int* __restrict__ cntp = priv + (size_t)(8 + r) * n;
    if (i < E) {
        atomicAdd(&degp[src[i]], 1);
        atomicAdd(&cntp[dst[i]], 1);
    }
}

// ---- kernel 2: reduce 8 copies -> deg,cnt; dinv; CSR row allocation (wave scan + 1 atomic/wave) ----
__global__ void k_reduce_alloc(const int* __restrict__ priv, int n,
                               float* __restrict__ dinv, int* __restrict__ cnt_out,
                               int* __restrict__ row_start, int* __restrict__ total) {
    int i = blockIdx.x * blockDim.x + threadIdx.x;
    int lane = threadIdx.x & 63;
    int c = 0;
    if (i < n) {
        int dg = 0;
        #pragma unroll
        for (int r = 0; r < 8; ++r) {
            dg += priv[(size_t)r * n + i];
            c  += priv[(size_t)(8 + r) * n + i];
        }
        float d = (float)dg;
        dinv[i] = d > 0.f ? rsqrtf(d) : 0.f;
        cnt_out[i] = c;
    }
    int incl = c;
    #pragma unroll
    for (int off = 1; off < 64; off <<= 1) {
        int v = __shfl_up(incl, off);
        if (lane >= off) incl += v;
    }
    int wtot = __shfl(incl, 63);
    int base = 0;
    if (lane == 63) base = atomicAdd(total, wtot);
    base = __shfl(base, 63);
    if (i < n) row_start[i] = base + incl - c;
}

// ---- kernel 3: fill CSR (by dst): fused {src, norm_bits} int2 ----
__global__ void k_fill(const int* __restrict__ src, const int* __restrict__ dst, int E,
                       const float* __restrict__ dinv, const int* __restrict__ row_start,
                       int* __restrict__ cursor, int2* __restrict__ csr) {
    int i = blockIdx.x * blockDim.x + threadIdx.x;
    if (i < E) {
        int s = src[i], d = dst[i];
        int pos = atomicAdd(&cursor[d], 1);
        int2 v;
        v.x = s;
        v.y = __float_as_int(-dinv[s] * dinv[d]);
        csr[row_start[d] + pos] = v;
    }
}

// ---- kernel 4: fp32 -> bf16 bulk convert ----
__global__ void k_tobf(const float* __restrict__ x, short* __restrict__ xbf, int total8) {
    int i = blockIdx.x * blockDim.x + threadIdx.x;
    if (i >= total8) return;
    const float4* s = (const float4*)x + (size_t)i * 2;
    float4 a = s[0], b = s[1];
    short8 o;
    o[0] = f2bf(a.x); o[1] = f2bf(a.y); o[2] = f2bf(a.z); o[3] = f2bf(a.w);
    o[4] = f2bf(b.x); o[5] = f2bf(b.y); o[6] = f2bf(b.z); o[7] = f2bf(b.w);
    ((short8*)xbf)[i] = o;
}

// ---- kernel 5: lhat gather, bf16 input. Wave = 1 row; 4 groups of 16 lanes;
//      each group processes 2 edges per iteration (4 gathers in flight w/ unroll 2).
template <int OUT_BF>
__global__ void k_gather_bf(const short* __restrict__ xbf, const int* __restrict__ row_start,
                            const int* __restrict__ cnt, const int2* __restrict__ csr,
                            void* __restrict__ outp, int n) {
    int row = blockIdx.x * 4 + (threadIdx.x >> 6);
    if (row >= n) return;
    int lane = threadIdx.x & 63;
    int gr = lane >> 4, lc = lane & 15;
    int base = row_start[row];
    int deg = cnt[row];
    float acc[8];
    #pragma unroll
    for (int t = 0; t < 8; ++t) acc[t] = 0.f;
    #pragma unroll 2
    for (int j = 0; j < deg; j += 8) {
        int j0 = j + gr, j1 = j + gr + 4;
        bool v0 = j0 < deg, v1 = j1 < deg;
        int2 sw0 = csr[base + (v0 ? j0 : 0)];
        int2 sw1 = csr[base + (v1 ? j1 : 0)];
        float w0 = v0 ? __int_as_float(sw0.y) : 0.f;
        float w1 = v1 ? __int_as_float(sw1.y) : 0.f;
        short8 xv0 = *(const short8*)(xbf + (size_t)sw0.x * 128 + lc * 8);
        short8 xv1 = *(const short8*)(xbf + (size_t)sw1.x * 128 + lc * 8);
        #pragma unroll
        for (int t = 0; t < 8; ++t) {
            acc[t] = fmaf(w0, bf2f(xv0[t]), acc[t]);
            acc[t] = fmaf(w1, bf2f(xv1[t]), acc[t]);
        }
    }
    #pragma unroll
    for (int t = 0; t < 8; ++t) {
        acc[t] += __shfl_xor(acc[t], 32);
        acc[t] += __shfl_xor(acc[t], 16);
    }
    if (gr == 0) {
        if (OUT_BF) {
            short8 o;
            #pragma unroll
            for (int t = 0; t < 8; ++t) o[t] = f2bf(acc[t]);
            *(short8*)((short*)outp + (size_t)row * 128 + lc * 8) = o;
        } else {
            float4 a, b;
            a.x = acc[0]; a.y = acc[1]; a.z = acc[2]; a.w = acc[3];
            b.x = acc[4]; b.y = acc[5]; b.z = acc[6]; b.w = acc[7];
            float4* op = (float4*)((float*)outp + (size_t)row * 128 + lc * 8);
            op[0] = a; op[1] = b;
        }
    }
}

// ---- kernel 6: effective weights, TRANSPOSED bf16: WT[c][h*128+k] ----
__global__ void k_wefft(const float* __restrict__ W, short* __restrict__ WT) {
    int i = blockIdx.x * blockDim.x + threadIdx.x;
    if (i < 16384) {
        int k = i >> 7, c = i & 127;
        float w0 = W[i], w1 = W[16384 + i], w2 = W[32768 + i];
        WT[(size_t)c * 384 + k]       = f2bf(w0 - w2);
        WT[(size_t)c * 384 + 128 + k] = f2bf(w1);
        WT[(size_t)c * 384 + 256 + k] = f2bf(2.f * w2);
    }
}

// ---- kernel 7: bf16 MFMA GEMM: out = [x|tx1|z] @ Weff + bias, PReLU, BN stats ----
__global__ __launch_bounds__(256) void k_gemm_mfma(
        const short* __restrict__ A0bf, const short* __restrict__ A1bf,
        const float* __restrict__ A2f,
        const short* __restrict__ WT, const float* __restrict__ bias,
        const float* __restrict__ aprelu, float* __restrict__ out,
        float* __restrict__ sums, float* __restrict__ sumsq, int n) {
    __shared__ __align__(16) short Alds[128 * 64];
    __shared__ __align__(16) short Blds[128 * 64];

    int t = threadIdx.x;
    int lane = t & 63;
    int w = t >> 6;
    int wr = w >> 1, wc = w & 1;
    int row0 = blockIdx.x * 128;

    f32x4 acc[4][4];
    #pragma unroll
    for (int m = 0; m < 4; ++m)
        #pragma unroll
        for (int nn = 0; nn < 4; ++nn) acc[m][nn] = (f32x4){0.f, 0.f, 0.f, 0.f};

    #pragma unroll
    for (int ht = 0; ht < 6; ++ht) {
        const int h = ht >> 1, c = ht & 1;

        if (ht) __syncthreads();

        // --- stage B tile (WT) via global_load_lds, pre-swizzled src
        #pragma unroll
        for (int i = 0; i < 4; ++i) {
            int rB = w * 32 + i * 8 + (lane >> 3);
            int blkB = (lane & 7) ^ (rB & 7);
            const short* srcB = WT + (size_t)rB * 384 + h * 128 + c * 64 + blkB * 8;
            __builtin_amdgcn_global_load_lds(
                (const __attribute__((address_space(1))) void*)srcB,
                (__attribute__((address_space(3))) void*)&Blds[(w * 32 + i * 8) * 64],
                16, 0, 0);
        }
        // --- stage A tile
        if (h < 2) {
            const short* Abf = (h == 0) ? A0bf : A1bf;
            #pragma unroll
            for (int i = 0; i < 4; ++i) {
                int rA = w * 32 + i * 8 + (lane >> 3);
                int grow = row0 + rA; if (grow >= n) grow = n - 1;
                int blkA = (lane & 7) ^ (rA & 7);
                const short* srcA = Abf + (size_t)grow * 128 + c * 64 + blkA * 8;
                __builtin_amdgcn_global_load_lds(
                    (const __attribute__((address_space(1))) void*)srcA,
                    (__attribute__((address_space(3))) void*)&Alds[(w * 32 + i * 8) * 64],
                    16, 0, 0);
            }
        } else {
            // fp32 z from d_out: reg-stage + convert (thread owns half a row)
            int r = t >> 1;
            int half = t & 1;
            int grow = row0 + r; if (grow >= n) grow = n - 1;
            const float4* src = (const float4*)(A2f + (size_t)grow * 128 + c * 64 + half * 32);
            float4 v[8];
            #pragma unroll
            for (int j = 0; j < 8; ++j) v[j] = src[j];
            #pragma unroll
            for (int jj = 0; jj < 4; ++jj) {
                short8 o;
                float4 a = v[jj * 2], b = v[jj * 2 + 1];
                o[0] = f2bf(a.x); o[1] = f2bf(a.y); o[2] = f2bf(a.z); o[3] = f2bf(a.w);
                o[4] = f2bf(b.x); o[5] = f2bf(b.y); o[6] = f2bf(b.z); o[7] = f2bf(b.w);
                int blk = (half * 4 + jj) ^ (r & 7);
                *(short8*)((char*)Alds + r * 128 + blk * 16) = o;
            }
        }
        __syncthreads();

        // --- MFMA: 2 k-subtiles of 32
        #pragma unroll
        for (int kk = 0; kk < 2; ++kk) {
            short8 af[4], bfr[4];
            #pragma unroll
            for (int m = 0; m < 4; ++m) {
                int row = wr * 64 + m * 16 + (lane & 15);
                int blk = (kk * 4 + (lane >> 4)) ^ (row & 7);
                af[m] = *(const short8*)((const char*)Alds + row * 128 + blk * 16);
            }
            #pragma unroll
            for (int nn = 0; nn < 4; ++nn) {
                int col = wc * 64 + nn * 16 + (lane & 15);
                int blk = (kk * 4 + (lane >> 4)) ^ (col & 7);
                bfr[nn] = *(const short8*)((const char*)Blds + col * 128 + blk * 16);
            }
            #pragma unroll
            for (int m = 0; m < 4; ++m)
                #pragma unroll
                for (int nn = 0; nn < 4; ++nn)
                    acc[m][nn] = __builtin_amdgcn_mfma_f32_16x16x32_bf16(
                        af[m], bfr[nn], acc[m][nn], 0, 0, 0);
        }
    }

    // --- epilogue: bias + PReLU + store + BN stats
    float ap = aprelu[0];
    #pragma unroll
    for (int nn = 0; nn < 4; ++nn) {
        int col = wc * 64 + nn * 16 + (lane & 15);
        float bs = bias[col];
        float s = 0.f, q = 0.f;
        #pragma unroll
        for (int m = 0; m < 4; ++m) {
            int rbase = row0 + wr * 64 + m * 16 + (lane >> 4) * 4;
            #pragma unroll
            for (int r = 0; r < 4; ++r) {
                int row = rbase + r;
                if (row < n) {
                    float o = acc[m][nn][r] + bs;
                    o = o >= 0.f ? o : ap * o;
                    out[(size_t)row * 128 + col] = o;
                    s += o; q = fmaf(o, o, q);
                }
            }
        }
        s += __shfl_xor(s, 16); s += __shfl_xor(s, 32);
        q += __shfl_xor(q, 16); q += __shfl_xor(q, 32);
        if ((lane >> 4) == 0) {
            atomicAddF(&sums[col], s);
            atomicAddF(&sumsq[col], q);
        }
    }
}

// ---- kernel 8: BN scale/shift from stats ----
__global__ void k_bnfinal(const float* __restrict__ sums, const float* __restrict__ sumsq,
                          const float* __restrict__ gamma, const float* __restrict__ beta,
                          float* __restrict__ bnp, float n) {
    int c = threadIdx.x;
    float mean = sums[c] / n;
    float var = sumsq[c] / n - mean * mean;
    float sc = gamma[c] * rsqrtf(var + EPS);
    bnp[c] = sc;
    bnp[128 + c] = beta[c] - mean * sc;
}

// ---- kernel 9: apply BN in place ----
__global__ void k_bnapply(float* __restrict__ out, const float* __restrict__ bnp, int total4) {
    int i = blockIdx.x * blockDim.x + threadIdx.x;
    if (i >= total4) return;
    float4 v = ((float4*)out)[i];
    int c = (i * 4) & 127;
    float4 sc = *(const float4*)&bnp[c];
    float4 sh = *(const float4*)&bnp[128 + c];
    v.x = fmaf(v.x, sc.x, sh.x);
    v.y = fmaf(v.y, sc.y, sh.y);
    v.z = fmaf(v.z, sc.z, sh.z);
    v.w = fmaf(v.w, sc.w, sh.w);
    ((float4*)out)[i] = v;
}

extern "C" void kernel_launch(void* const* d_in, const int* in_sizes, int n_in,
                              void* d_out, int out_size, void* d_ws, size_t ws_size,
                              hipStream_t stream) {
    const float* x      = (const float*)d_in[0];
    const int*   ei     = (const int*)d_in[1];
    const float* W      = (const float*)d_in[2];
    const float* bias   = (const float*)d_in[3];
    const float* aprelu = (const float*)d_in[4];
    const float* gamma  = (const float*)d_in[5];
    const float* beta   = (const float*)d_in[6];
    int n = in_sizes[0] / 128;
    int E = in_sizes[1] / 2;
    const int* src = ei;
    const int* dst = ei + E;

    char* ws = (char*)d_ws;
    size_t off = 0;
    auto carve = [&](size_t bytes) {
        char* p = ws + off;
        off = (off + bytes + 511) & ~(size_t)511;
        return p;
    };
    short* xbf      = (short*)carve((size_t)n * 128 * 2);
    short* tx1bf    = (short*)carve((size_t)n * 128 * 2);
    size_t zbeg = off;
    int*   priv     = (int*)carve((size_t)n * 16 * 4);   // 8 deg copies + 8 cnt copies
    int*   cursor   = (int*)carve((size_t)n * 4);
    int*   total    = (int*)carve(256);
    float* sums     = (float*)carve(512);
    float* sumsq    = (float*)carve(512);
    size_t zend = off;
    float* dinv     = (float*)carve((size_t)n * 4);
    int*   cnt_dst  = (int*)carve((size_t)n * 4);
    int*   row_start= (int*)carve((size_t)n * 4);
    int2*  csr      = (int2*)carve((size_t)E * 8);
    short* WT       = (short*)carve((size_t)128 * 384 * 2);
    float* bnp      = (float*)carve(256 * 4);
    (void)ws_size; (void)n_in; (void)out_size;

    float* z = (float*)d_out;   // z (fp32) lives in d_out; GEMM reads own rows before writing

    hipMemsetAsync(ws + zbeg, 0, zend - zbeg, stream);

    int eb = (E + 255) / 256;
    int nb = (n + 255) / 256;
    k_count_priv<<<eb, 256, 0, stream>>>(src, dst, E, priv, n);
    k_reduce_alloc<<<nb, 256, 0, stream>>>(priv, n, dinv, cnt_dst, row_start, total);
    k_fill<<<eb, 256, 0, stream>>>(src, dst, E, dinv, row_start, cursor, csr);
    k_wefft<<<64, 256, 0, stream>>>(W, WT);
    int t8 = n * 16;   // n*128/8
    k_tobf<<<(t8 + 255) / 256, 256, 0, stream>>>(x, xbf, t8);
    int gb = (n + 3) / 4;
    k_gather_bf<1><<<gb, 256, 0, stream>>>(xbf, row_start, cnt_dst, csr, tx1bf, n);
    k_gather_bf<0><<<gb, 256, 0, stream>>>(tx1bf, row_start, cnt_dst, csr, z, n);
    int mb = (n + 127) / 128;
    k_gemm_mfma<<<mb, 256, 0, stream>>>(xbf, tx1bf, z, WT, bias, aprelu, (float*)d_out,
                                        sums, sumsq, n);
    k_bnfinal<<<1, 128, 0, stream>>>(sums, sumsq, gamma, beta, bnp, (float)n);
    int total4 = n * 32;
    k_bnapply<<<(total4 + 255) / 256, 256, 0, stream>>>((float*)d_out, bnp, total4);
}